// Round 1
// baseline (56.373 us; speedup 1.0000x reference)
//
#include <hip/hip_runtime.h>
#include <stdint.h>

#define INF 8192        // IN features
#define OUTF 8192       // OUT features
#define TOK 16          // tokens (2*8)
#define KSPLIT 8
#define KR (INF / KSPLIT)          // 1024 K per block
#define ROWS_PER_BLOCK 64          // 4 waves * 16 rows
#define LDS_STRIDE (KR + 8)        // bf16 elems, padded (1032)

typedef __attribute__((ext_vector_type(8))) short short8;
typedef __attribute__((ext_vector_type(4))) short short4v;
typedef __attribute__((ext_vector_type(4))) float float4v;
typedef __attribute__((ext_vector_type(4))) int int4v;

__device__ __forceinline__ short f2bf(float f) {
    uint32_t u = __builtin_bit_cast(uint32_t, f);
    u += 0x7fffu + ((u >> 16) & 1u);   // round-to-nearest-even
    return (short)(u >> 16);
}

// Stage x[0..15][k0..k0+KR) into LDS as bf16 (padded stride).
__device__ __forceinline__ void stage_x(const float* __restrict__ x, short* xs,
                                        int k0, int tid) {
    #pragma unroll
    for (int it = 0; it < (TOK * KR / 4) / 256; ++it) {   // 16 iters
        int idx = tid + it * 256;
        int t  = idx >> 8;        // KR/4 = 256 float4 per token row
        int kq = idx & 255;
        float4v xv = *reinterpret_cast<const float4v*>(x + (size_t)t * INF + k0 + kq * 4);
        short4v h;
        h[0] = f2bf(xv[0]); h[1] = f2bf(xv[1]); h[2] = f2bf(xv[2]); h[3] = f2bf(xv[3]);
        *reinterpret_cast<short4v*>(xs + t * LDS_STRIDE + kq * 4) = h;
    }
}

// Inner K-loop over KR for one wave: 16 output rows r0..r0+15, tokens 0..15.
__device__ __forceinline__ float4v kloop(const short* xs,
                                         const int* __restrict__ qrow,   // q + r*INF + k0 + kg*8
                                         const float* __restrict__ srow, // scales + r*(INF/32) + k0/32
                                         int lane, float4v acc) {
    int col = lane & 15;
    int kg  = lane >> 4;
    const short* aptr = xs + col * LDS_STRIDE + kg * 8;

    int4v qa = *reinterpret_cast<const int4v*>(qrow);
    int4v qb = *reinterpret_cast<const int4v*>(qrow + 4);
    float s  = srow[0];

    #pragma unroll 4
    for (int i = 0; i < KR / 32; ++i) {
        int ip = (i < KR / 32 - 1) ? i + 1 : i;
        int4v na = *reinterpret_cast<const int4v*>(qrow + ip * 32);
        int4v nb = *reinterpret_cast<const int4v*>(qrow + ip * 32 + 4);
        float ns = srow[ip];

        float m = -127.0f * s;
        short8 bfrag;
        bfrag[0] = f2bf(fmaf((float)qa[0], s, m));
        bfrag[1] = f2bf(fmaf((float)qa[1], s, m));
        bfrag[2] = f2bf(fmaf((float)qa[2], s, m));
        bfrag[3] = f2bf(fmaf((float)qa[3], s, m));
        bfrag[4] = f2bf(fmaf((float)qb[0], s, m));
        bfrag[5] = f2bf(fmaf((float)qb[1], s, m));
        bfrag[6] = f2bf(fmaf((float)qb[2], s, m));
        bfrag[7] = f2bf(fmaf((float)qb[3], s, m));

        short8 afrag = *reinterpret_cast<const short8*>(aptr + i * 32);

        acc = __builtin_amdgcn_mfma_f32_16x16x32_bf16(afrag, bfrag, acc, 0, 0, 0);

        qa = na; qb = nb; s = ns;
    }
    return acc;
}

__global__ __launch_bounds__(256, 4) void gemm_q8_part(
    const float* __restrict__ x, const int* __restrict__ qw,
    const float* __restrict__ scales, float* __restrict__ pbuf)
{
    __shared__ short xs[TOK * LDS_STRIDE];
    int rg = blockIdx.x >> 3;          // 0..127 row groups
    int ks = blockIdx.x & 7;           // 0..7 k splits
    int k0 = ks * KR;
    int tid = threadIdx.x;

    stage_x(x, xs, k0, tid);
    __syncthreads();

    int wave = tid >> 6;
    int lane = tid & 63;
    int col  = lane & 15;
    int kg   = lane >> 4;
    int r0 = rg * ROWS_PER_BLOCK + wave * 16;
    int r  = r0 + col;

    const int*   qrow = qw + (size_t)r * INF + k0 + kg * 8;
    const float* srow = scales + (size_t)r * (INF / 32) + (k0 >> 5);

    float4v acc = {0.f, 0.f, 0.f, 0.f};
    acc = kloop(xs, qrow, srow, lane, acc);

    // C mapping: col = lane&15 (out row r), row = (lane>>4)*4 + i (token t)
    float* pb = pbuf + (size_t)ks * TOK * OUTF;
    #pragma unroll
    for (int i = 0; i < 4; ++i) {
        int t = kg * 4 + i;
        pb[(size_t)t * OUTF + r0 + col] = acc[i];
    }
}

__global__ __launch_bounds__(256) void reduce_bias_k(
    const float* __restrict__ pbuf, const float* __restrict__ bias,
    float* __restrict__ out)
{
    int gid = blockIdx.x * 256 + threadIdx.x;   // 32768 threads, float4 each
    int f = gid * 4;
    int t = f >> 13;       // /8192
    int r = f & (OUTF - 1);
    float4v a = *reinterpret_cast<const float4v*>(bias + r);
    #pragma unroll
    for (int s = 0; s < KSPLIT; ++s) {
        float4v p = *reinterpret_cast<const float4v*>(pbuf + (size_t)(s * TOK + t) * OUTF + r);
        a += p;
    }
    *reinterpret_cast<float4v*>(out + f) = a;
}

// Fallback when d_ws is too small: full-K per block, direct write (+bias).
__global__ __launch_bounds__(256, 4) void gemm_q8_direct(
    const float* __restrict__ x, const int* __restrict__ qw,
    const float* __restrict__ scales, const float* __restrict__ bias,
    float* __restrict__ out)
{
    __shared__ short xs[TOK * LDS_STRIDE];
    int rg = blockIdx.x;               // 0..127
    int tid = threadIdx.x;
    int wave = tid >> 6;
    int lane = tid & 63;
    int col  = lane & 15;
    int kg   = lane >> 4;
    int r0 = rg * ROWS_PER_BLOCK + wave * 16;
    int r  = r0 + col;

    float4v acc = {0.f, 0.f, 0.f, 0.f};
    for (int ks = 0; ks < KSPLIT; ++ks) {
        int k0 = ks * KR;
        __syncthreads();
        stage_x(x, xs, k0, tid);
        __syncthreads();
        const int*   qrow = qw + (size_t)r * INF + k0 + kg * 8;
        const float* srow = scales + (size_t)r * (INF / 32) + (k0 >> 5);
        acc = kloop(xs, qrow, srow, lane, acc);
    }
    #pragma unroll
    for (int i = 0; i < 4; ++i) {
        int t = kg * 4 + i;
        out[(size_t)t * OUTF + r0 + col] = acc[i] + bias[r0 + col];
    }
}

extern "C" void kernel_launch(void* const* d_in, const int* in_sizes, int n_in,
                              void* d_out, int out_size, void* d_ws, size_t ws_size,
                              hipStream_t stream) {
    const float* x      = (const float*)d_in[0];
    const int*   qw     = (const int*)d_in[1];
    const float* scales = (const float*)d_in[2];
    const float* bias   = (const float*)d_in[3];
    float* out = (float*)d_out;

    size_t need = (size_t)KSPLIT * TOK * OUTF * sizeof(float);   // 4 MB
    if (ws_size >= need) {
        float* pbuf = (float*)d_ws;
        gemm_q8_part<<<(OUTF / ROWS_PER_BLOCK) * KSPLIT, 256, 0, stream>>>(x, qw, scales, pbuf);
        reduce_bias_k<<<(TOK * OUTF / 4) / 256, 256, 0, stream>>>(pbuf, bias, out);
    } else {
        gemm_q8_direct<<<OUTF / ROWS_PER_BLOCK, 256, 0, stream>>>(x, qw, scales, bias, out);
    }
}